// Round 9
// baseline (413.190 us; speedup 1.0000x reference)
//
#include <hip/hip_runtime.h>

typedef unsigned short u16;
typedef unsigned int u32;
typedef unsigned long long u64;
typedef __attribute__((ext_vector_type(4))) float f32x4;
typedef __attribute__((ext_vector_type(4))) unsigned short u16x4;
typedef __attribute__((ext_vector_type(8))) short short8;

#define GLOAD16(G, L) __builtin_amdgcn_global_load_lds( \
    (const __attribute__((address_space(1))) void*)(G), \
    (__attribute__((address_space(3))) void*)(L), 16, 0, 0)

__device__ __forceinline__ u16 f2bf(float f) {
  union { float f; unsigned u; } c; c.f = f;
  unsigned u = c.u;
  u += 0x7FFFu + ((u >> 16) & 1u);
  return (u16)(u >> 16);
}

__device__ __forceinline__ void store_out(u16* p, float v) { *p = f2bf(v); }
__device__ __forceinline__ void store_out(float* p, float v) { *p = v; }

// ---------- elementwise f32 -> bf16 ----------
__global__ void k_cvt(const float* __restrict__ in, u16* __restrict__ out, int n4) {
  int i = blockIdx.x * blockDim.x + threadIdx.x;
  if (i >= n4) return;
  const f32x4 v = *(const f32x4*)(in + (size_t)i * 4);
  u16x4 o;
  o[0] = f2bf(v[0]); o[1] = f2bf(v[1]); o[2] = f2bf(v[2]); o[3] = f2bf(v[3]);
  *(u16x4*)(out + (size_t)i * 4) = o;
}

// ---------- transpose+convert+scale: src[R][C] f32 -> dst[C][R] bf16 ----------
__global__ void k_tcvt(const float* __restrict__ src, u16* __restrict__ dst,
                       int R, int C, float scale) {
  __shared__ float t[32][33];
  int bx = blockIdx.x * 32;
  int by = blockIdx.y * 32;
  int tx = threadIdx.x, ty = threadIdx.y;
  #pragma unroll
  for (int j = 0; j < 32; j += 8)
    t[ty + j][tx] = src[(size_t)(by + ty + j) * C + bx + tx];
  __syncthreads();
  #pragma unroll
  for (int j = 0; j < 32; j += 8)
    dst[(size_t)(bx + ty + j) * R + by + tx] = f2bf(t[tx][ty + j] * scale);
}

// ---------- transpose V with k-permutation ----------
// vt[b*1024 + d][tblk*64 + i(k)] = kv[b*2048 + t][1024 + d],  k = t & 63,
// i(k) = ((k>>2)&3)*16 + (k>>4)*4 + (k&3)  (so PV fragments are 16B-contiguous)
__global__ void k_tv(const u16* __restrict__ kv, u16* __restrict__ vt) {
  __shared__ u16 sh[32][34];
  int b = blockIdx.z;
  int tb = blockIdx.x * 32;
  int db = blockIdx.y * 32;
  int tx = threadIdx.x, ty = threadIdx.y;
  #pragma unroll
  for (int j = 0; j < 32; j += 8)
    sh[ty + j][tx] = kv[(size_t)(b * 2048 + tb + ty + j) * 2048 + 1024 + db + tx];
  __syncthreads();
  int t = tb + tx;
  int k6 = t & 63;
  int colp = (t & ~63) | (((k6 >> 2) & 3) << 4) | ((k6 >> 4) << 2) | (k6 & 3);
  #pragma unroll
  for (int j = 0; j < 32; j += 8)
    vt[(size_t)(b * 1024 + db + ty + j) * 2048 + colp] = sh[tx][ty + j];
}

// ---------- pack mask into bits: bits[(b*2048+q)*64 + k/32] ----------
__global__ void k_pm(const int* __restrict__ mask, unsigned* __restrict__ bits, int nw) {
  int w = blockIdx.x * blockDim.x + threadIdx.x;
  if (w >= nw) return;
  const int4* p = (const int4*)(mask + (size_t)w * 32);
  unsigned b = 0;
  #pragma unroll
  for (int j = 0; j < 8; ++j) {
    int4 v = p[j];
    b |= (v.x != 0 ? 1u : 0u) << (j * 4);
    b |= (v.y != 0 ? 1u : 0u) << (j * 4 + 1);
    b |= (v.z != 0 ? 1u : 0u) << (j * 4 + 2);
    b |= (v.w != 0 ? 1u : 0u) << (j * 4 + 3);
  }
  bits[w] = b;
}

// ---------- bf16 GEMM: C[M][N] = A[M][K] @ Bt[N][K]^T, tile BM x BN, BK=64 ----------
template <int BM, int BN, typename OUT_T>
__global__ __launch_bounds__(256) void k_gemm(
    const u16* __restrict__ A, const u16* __restrict__ Bt,
    OUT_T* __restrict__ C, int M, int N, int K)
{
  constexpr int MI = BM / 32, NI = BN / 32;
  __shared__ u16 As[BM * 64];
  __shared__ u16 Bs[BN * 64];
  const int tid = threadIdx.x;
  const int lane = tid & 63;
  const int w = tid >> 6;
  const int wr = w >> 1, wc = w & 1;
  const int l16 = lane & 15, lh = lane >> 4;
  const size_t tm = blockIdx.x, tn = blockIdx.y;

  f32x4 acc[MI][NI] = {};

  for (int kt = 0; kt < K; kt += 64) {
    #pragma unroll
    for (int i = 0; i < BM / 32; ++i) {
      int flat = i * 256 + tid;
      int row = flat >> 3, cb = flat & 7;
      GLOAD16(A + (tm * BM + row) * K + kt + ((cb ^ (row & 7)) * 8),
              (char*)As + flat * 16);
    }
    #pragma unroll
    for (int i = 0; i < BN / 32; ++i) {
      int flat = i * 256 + tid;
      int row = flat >> 3, cb = flat & 7;
      GLOAD16(Bt + (tn * BN + row) * K + kt + ((cb ^ (row & 7)) * 8),
              (char*)Bs + flat * 16);
    }
    __syncthreads();
    #pragma unroll
    for (int kk = 0; kk < 2; ++kk) {
      short8 a[MI], b[NI];
      #pragma unroll
      for (int mi = 0; mi < MI; ++mi) {
        int row = wr * (BM / 2) + mi * 16 + l16;
        a[mi] = *(const short8*)&As[row * 64 + ((kk * 32 + lh * 8) ^ ((row & 7) * 8))];
      }
      #pragma unroll
      for (int ni = 0; ni < NI; ++ni) {
        int row = wc * (BN / 2) + ni * 16 + l16;
        b[ni] = *(const short8*)&Bs[row * 64 + ((kk * 32 + lh * 8) ^ ((row & 7) * 8))];
      }
      #pragma unroll
      for (int mi = 0; mi < MI; ++mi)
        #pragma unroll
        for (int ni = 0; ni < NI; ++ni)
          acc[mi][ni] = __builtin_amdgcn_mfma_f32_16x16x32_bf16(a[mi], b[ni], acc[mi][ni], 0, 0, 0);
    }
    __syncthreads();
  }
  #pragma unroll
  for (int mi = 0; mi < MI; ++mi)
    #pragma unroll
    for (int ni = 0; ni < NI; ++ni)
      #pragma unroll
      for (int r = 0; r < 4; ++r) {
        size_t row = tm * BM + wr * (BM / 2) + mi * 16 + lh * 4 + r;
        size_t col = tn * BN + wc * (BN / 2) + ni * 16 + l16;
        store_out(&C[row * N + col], acc[mi][ni][r]);
      }
}

// ---------- fused flash attention v9: LDS-free, barrier-free, wave-independent ----------
// 1024 blocks x 256 thr = 4096 waves; wave = (h, batch, 16 q-rows), sweeps kt=0..31.
// K fragments read DIRECTLY from global (L2-resident; 16 rows x 64B lines per load,
// same line count as a coalesced load). V via k_tv permutation (16B/lane, R7-proven).
// Registers double-buffer K/bias/mask one step ahead; V issued early in-step.
// No s_barrier, no LDS, no vmcnt(0): the compiler's dataflow waitcnts form the
// pipeline; waves free-run and self-skew, hiding HBM latency with 2 waves/SIMD.
__global__ __launch_bounds__(256, 2) void k_attn(
    const u16* __restrict__ Qp,      // [4096][1024], pre-scaled by 1/8
    const u16* __restrict__ KVp,     // [4096][2048] (cols 0..1023 = K heads)
    const u16* __restrict__ Vt,      // [2048][2048] permuted (see k_tv)
    const float* __restrict__ bias,  // [16][2048][2048]
    const unsigned* __restrict__ mbits, // [2][2048][64]
    u16* __restrict__ Ob)            // [4096][1024]
{
  const int tid = threadIdx.x;
  const int lane = tid & 63;
  const int w = tid >> 6;
  // XCD swizzle: consecutive bids -> same XCD gets contiguous sid range; each XCD
  // covers 2 heads (K/V working set ~4MB = XCD L2). 1024 % 8 == 0 -> bijective.
  const int bid = blockIdx.x;
  const int sid = (bid & 7) * 128 + (bid >> 3);
  const int h  = sid >> 6;
  const int bw = (sid >> 5) & 1;
  const int qt = (sid & 31) * 4 + w;   // 0..127 (16 q-rows each)
  const int l16 = lane & 15, lh = lane >> 4;
  const int q = qt * 16 + l16;

  // K fragment base: row = kt*64 + ni*16 + l16 (k index), col = h*64 + kk*32 + lh*8
  const u16* kfp = KVp + ((size_t)bw * 2048 + l16) * 2048 + h * 64 + lh * 8;
  // V fragment base: row = bw*1024 + h*64 + di*16 + l16 (d), col = kt*64 + lh*16 + kk*8
  const u16* vfp = Vt + ((size_t)(bw * 1024 + h * 64 + l16)) * 2048 + lh * 16;

  short8 qf0, qf1;
  {
    size_t row = (size_t)bw * 2048 + q;
    qf0 = *(const short8*)&Qp[row * 1024 + h * 64 + lh * 8];
    qf1 = *(const short8*)&Qp[row * 1024 + h * 64 + 32 + lh * 8];
  }
  const float* bsrc = bias + ((size_t)h * 2048 + q) * 2048 + lh * 4;
  const u64*   msrc = (const u64*)(mbits + ((size_t)bw * 2048 + q) * 64);

  f32x4 oacc[4] = {};
  f32x4 lpv = {};
  short8 kA[8], kB[8];
  f32x4 bA[4], bB[4];
  u64 mA, mB;

#define LOADSET(KC, BC, MC, KT) do {                                                    \
    _Pragma("unroll")                                                                   \
    for (int ni_ = 0; ni_ < 4; ++ni_) {                                                 \
      _Pragma("unroll")                                                                 \
      for (int kk_ = 0; kk_ < 2; ++kk_)                                                 \
        KC[ni_ * 2 + kk_] = *(const short8*)(kfp + ((size_t)((KT) * 64 + ni_ * 16)) * 2048 + kk_ * 32); \
      BC[ni_] = *(const f32x4*)(bsrc + (size_t)(KT) * 64 + ni_ * 16);                   \
    }                                                                                   \
    MC = msrc[(KT)];                                                                    \
  } while (0)

  // prologue: fill both register sets (kt=0 -> A, kt=1 -> B)
  LOADSET(kA, bA, mA, 0);
  LOADSET(kB, bB, mB, 1);

#define STEP(KT, KC, BC, MC) do {                                                       \
    f32x4 s_[4];                                                                        \
    s_[0] = BC[0]; s_[1] = BC[1]; s_[2] = BC[2]; s_[3] = BC[3];                         \
    const unsigned tlo_ = (unsigned)(MC) >> (lh * 4);                                   \
    const unsigned thi_ = (unsigned)((MC) >> 32) >> (lh * 4);                           \
    _Pragma("unroll")                                                                   \
    for (int kk = 0; kk < 2; ++kk)                                                      \
      _Pragma("unroll")                                                                 \
      for (int ni = 0; ni < 4; ++ni)                                                    \
        s_[ni] = __builtin_amdgcn_mfma_f32_16x16x32_bf16(KC[ni * 2 + kk],               \
                     (kk ? qf1 : qf0), s_[ni], 0, 0, 0);                                \
    /* issue V for this step early: L2 latency hides under exp phase */                 \
    short8 vf_[8];                                                                      \
    _Pragma("unroll")                                                                   \
    for (int di = 0; di < 4; ++di)                                                      \
      _Pragma("unroll")                                                                 \
      for (int kk = 0; kk < 2; ++kk)                                                    \
        vf_[di * 2 + kk] = *(const short8*)(vfp + (size_t)di * 16 * 2048 + (size_t)(KT) * 64 + kk * 8); \
    /* refill this register set with kt+2 (clamped) */                                  \
    {                                                                                   \
      const int ktn_ = ((KT) + 2 < 32) ? (KT) + 2 : 31;                                 \
      LOADSET(KC, BC, MC, ktn_);                                                        \
    }                                                                                   \
    union pfu_ { u32 wd[4]; short8 v; };                                                \
    union pfu_ pf_[2];                                                                  \
    _Pragma("unroll")                                                                   \
    for (int ni = 0; ni < 4; ++ni) {                                                    \
      const unsigned tw_ = (ni < 2) ? tlo_ : thi_;                                      \
      _Pragma("unroll")                                                                 \
      for (int r = 0; r < 4; ++r) {                                                     \
        const unsigned bit_ = (tw_ >> ((ni & 1) * 16 + r)) & 1u;                        \
        s_[ni][r] = bit_ ? __expf(s_[ni][r]) : 0.f;                                     \
      }                                                                                 \
      lpv += s_[ni];                                                                    \
      asm("v_cvt_pk_bf16_f32 %0, %1, %2" : "=v"(pf_[ni >> 1].wd[2 * (ni & 1)])     : "v"(s_[ni][0]), "v"(s_[ni][1])); \
      asm("v_cvt_pk_bf16_f32 %0, %1, %2" : "=v"(pf_[ni >> 1].wd[2 * (ni & 1) + 1]) : "v"(s_[ni][2]), "v"(s_[ni][3])); \
    }                                                                                   \
    _Pragma("unroll")                                                                   \
    for (int kk = 0; kk < 2; ++kk)                                                      \
      _Pragma("unroll")                                                                 \
      for (int di = 0; di < 4; ++di)                                                    \
        oacc[di] = __builtin_amdgcn_mfma_f32_16x16x32_bf16(vf_[di * 2 + kk], pf_[kk].v, oacc[di], 0, 0, 0); \
  } while (0)

  for (int kt = 0; kt < 32; kt += 2) {
    STEP(kt,     kA, bA, mA);
    STEP(kt + 1, kB, bB, mB);
  }
#undef STEP
#undef LOADSET

  // ---- epilogue: reduce row-sum across lh groups, divide, pack, store ----
  float lpart = lpv[0] + lpv[1] + lpv[2] + lpv[3];
  lpart += __shfl_xor(lpart, 16);
  lpart += __shfl_xor(lpart, 32);
  float inv = 1.0f / lpart;
  size_t orow = (size_t)bw * 2048 + q;
  #pragma unroll
  for (int di = 0; di < 4; ++di)
    #pragma unroll
    for (int rp = 0; rp < 2; ++rp) {
      float v0 = oacc[di][2 * rp] * inv;
      float v1 = oacc[di][2 * rp + 1] * inv;
      u32 pk;
      asm("v_cvt_pk_bf16_f32 %0, %1, %2" : "=v"(pk) : "v"(v0), "v"(v1));
      *(u32*)&Ob[orow * 1024 + h * 64 + di * 16 + lh * 4 + rp * 2] = pk;
    }
}

extern "C" void kernel_launch(void* const* d_in, const int* in_sizes, int n_in,
                              void* d_out, int out_size, void* d_ws, size_t ws_size,
                              hipStream_t stream) {
  const float* query     = (const float*)d_in[0];
  const float* key_value = (const float*)d_in[1];
  const int*   mask      = (const int*)d_in[2];
  const float* bias      = (const float*)d_in[3];
  const float* Wq        = (const float*)d_in[4];
  const float* Wkv       = (const float*)d_in[5];
  const float* Wo        = (const float*)d_in[6];
  float* out = (float*)d_out;

  char* ws = (char*)d_ws;
  u16* qb   = (u16*)(ws);                    // 8 MiB  bf16 query
  u16* kvb  = (u16*)(ws + 8388608);          // 8 MiB  bf16 key_value
  u16* WqT  = (u16*)(ws + 16777216);         // 2 MiB  Wq^T * 0.125
  u16* WkvT = (u16*)(ws + 18874368);         // 4 MiB  Wkv^T
  u16* WoT  = (u16*)(ws + 23068672);         // 2 MiB  Wo^T
  u16* Qp   = (u16*)(ws + 25165824);         // 8 MiB  projected q
  u16* KVp  = (u16*)(ws + 33554432);         // 16 MiB projected kv
  u16* Vt   = (u16*)(ws + 50331648);         // 8 MiB  V transposed+permuted
  u16* Ob   = (u16*)(ws + 58720256);         // 8 MiB  attention out
  unsigned* mb = (unsigned*)(ws + 67108864); // 1 MiB  packed mask

  dim3 tb(32, 8);
  k_cvt<<<4096, 256, 0, stream>>>(query, qb, 1048576);
  k_cvt<<<4096, 256, 0, stream>>>(key_value, kvb, 1048576);
  k_tcvt<<<dim3(32, 32), tb, 0, stream>>>(Wq,  WqT,  1024, 1024, 0.125f);
  k_tcvt<<<dim3(64, 32), tb, 0, stream>>>(Wkv, WkvT, 1024, 2048, 1.0f);
  k_tcvt<<<dim3(32, 32), tb, 0, stream>>>(Wo,  WoT,  1024, 1024, 1.0f);
  k_pm<<<1024, 256, 0, stream>>>(mask, mb, 262144);
  k_gemm<64, 128, u16><<<dim3(64, 8),  256, 0, stream>>>(qb,  WqT,  Qp,  4096, 1024, 1024);
  k_gemm<64, 128, u16><<<dim3(64, 16), 256, 0, stream>>>(kvb, WkvT, KVp, 4096, 2048, 1024);
  k_tv<<<dim3(64, 32, 2), tb, 0, stream>>>(KVp, Vt);
  k_attn<<<1024, 256, 0, stream>>>(Qp, KVp, Vt, bias, mb, Ob);
  k_gemm<64, 128, float><<<dim3(64, 8), 256, 0, stream>>>(Ob, WoT, out, 4096, 1024, 1024);
}

// Round 10
// 325.097 us; speedup vs baseline: 1.2710x; 1.2710x over previous
//
#include <hip/hip_runtime.h>

typedef unsigned short u16;
typedef unsigned int u32;
typedef unsigned long long u64;
typedef __attribute__((ext_vector_type(4))) float f32x4;
typedef __attribute__((ext_vector_type(4))) unsigned short u16x4;
typedef __attribute__((ext_vector_type(8))) short short8;

#define GLOAD16(G, L) __builtin_amdgcn_global_load_lds( \
    (const __attribute__((address_space(1))) void*)(G), \
    (__attribute__((address_space(3))) void*)(L), 16, 0, 0)

__device__ __forceinline__ u16 f2bf(float f) {
  union { float f; unsigned u; } c; c.f = f;
  unsigned u = c.u;
  u += 0x7FFFu + ((u >> 16) & 1u);
  return (u16)(u >> 16);
}

__device__ __forceinline__ void store_out(u16* p, float v) { *p = f2bf(v); }
__device__ __forceinline__ void store_out(float* p, float v) { *p = v; }

// ---------- elementwise f32 -> bf16 ----------
__global__ void k_cvt(const float* __restrict__ in, u16* __restrict__ out, int n4) {
  int i = blockIdx.x * blockDim.x + threadIdx.x;
  if (i >= n4) return;
  const f32x4 v = *(const f32x4*)(in + (size_t)i * 4);
  u16x4 o;
  o[0] = f2bf(v[0]); o[1] = f2bf(v[1]); o[2] = f2bf(v[2]); o[3] = f2bf(v[3]);
  *(u16x4*)(out + (size_t)i * 4) = o;
}

// ---------- transpose+convert+scale: src[R][C] f32 -> dst[C][R] bf16 ----------
__global__ void k_tcvt(const float* __restrict__ src, u16* __restrict__ dst,
                       int R, int C, float scale) {
  __shared__ float t[32][33];
  int bx = blockIdx.x * 32;
  int by = blockIdx.y * 32;
  int tx = threadIdx.x, ty = threadIdx.y;
  #pragma unroll
  for (int j = 0; j < 32; j += 8)
    t[ty + j][tx] = src[(size_t)(by + ty + j) * C + bx + tx];
  __syncthreads();
  #pragma unroll
  for (int j = 0; j < 32; j += 8)
    dst[(size_t)(bx + ty + j) * R + by + tx] = f2bf(t[tx][ty + j] * scale);
}

// ---------- transpose V with k-permutation ----------
// vt[b*1024 + d][tblk*64 + i(k)] = kv[b*2048 + t][1024 + d],  k = t & 63,
// i(k) = ((k>>2)&3)*16 + (k>>4)*4 + (k&3)  (so PV fragments are 16B-contiguous)
__global__ void k_tv(const u16* __restrict__ kv, u16* __restrict__ vt) {
  __shared__ u16 sh[32][34];
  int b = blockIdx.z;
  int tb = blockIdx.x * 32;
  int db = blockIdx.y * 32;
  int tx = threadIdx.x, ty = threadIdx.y;
  #pragma unroll
  for (int j = 0; j < 32; j += 8)
    sh[ty + j][tx] = kv[(size_t)(b * 2048 + tb + ty + j) * 2048 + 1024 + db + tx];
  __syncthreads();
  int t = tb + tx;
  int k6 = t & 63;
  int colp = (t & ~63) | (((k6 >> 2) & 3) << 4) | ((k6 >> 4) << 2) | (k6 & 3);
  #pragma unroll
  for (int j = 0; j < 32; j += 8)
    vt[(size_t)(b * 1024 + db + ty + j) * 2048 + colp] = sh[tx][ty + j];
}

// ---------- pack mask into bits: bits[(b*2048+q)*64 + k/32] ----------
__global__ void k_pm(const int* __restrict__ mask, unsigned* __restrict__ bits, int nw) {
  int w = blockIdx.x * blockDim.x + threadIdx.x;
  if (w >= nw) return;
  const int4* p = (const int4*)(mask + (size_t)w * 32);
  unsigned b = 0;
  #pragma unroll
  for (int j = 0; j < 8; ++j) {
    int4 v = p[j];
    b |= (v.x != 0 ? 1u : 0u) << (j * 4);
    b |= (v.y != 0 ? 1u : 0u) << (j * 4 + 1);
    b |= (v.z != 0 ? 1u : 0u) << (j * 4 + 2);
    b |= (v.w != 0 ? 1u : 0u) << (j * 4 + 3);
  }
  bits[w] = b;
}

// ---------- bf16 GEMM: C[M][N] = A[M][K] @ Bt[N][K]^T, tile BM x BN, BK=64 ----------
template <int BM, int BN, typename OUT_T>
__global__ __launch_bounds__(256) void k_gemm(
    const u16* __restrict__ A, const u16* __restrict__ Bt,
    OUT_T* __restrict__ C, int M, int N, int K)
{
  constexpr int MI = BM / 32, NI = BN / 32;
  __shared__ u16 As[BM * 64];
  __shared__ u16 Bs[BN * 64];
  const int tid = threadIdx.x;
  const int lane = tid & 63;
  const int w = tid >> 6;
  const int wr = w >> 1, wc = w & 1;
  const int l16 = lane & 15, lh = lane >> 4;
  const size_t tm = blockIdx.x, tn = blockIdx.y;

  f32x4 acc[MI][NI] = {};

  for (int kt = 0; kt < K; kt += 64) {
    #pragma unroll
    for (int i = 0; i < BM / 32; ++i) {
      int flat = i * 256 + tid;
      int row = flat >> 3, cb = flat & 7;
      GLOAD16(A + (tm * BM + row) * K + kt + ((cb ^ (row & 7)) * 8),
              (char*)As + flat * 16);
    }
    #pragma unroll
    for (int i = 0; i < BN / 32; ++i) {
      int flat = i * 256 + tid;
      int row = flat >> 3, cb = flat & 7;
      GLOAD16(Bt + (tn * BN + row) * K + kt + ((cb ^ (row & 7)) * 8),
              (char*)Bs + flat * 16);
    }
    __syncthreads();
    #pragma unroll
    for (int kk = 0; kk < 2; ++kk) {
      short8 a[MI], b[NI];
      #pragma unroll
      for (int mi = 0; mi < MI; ++mi) {
        int row = wr * (BM / 2) + mi * 16 + l16;
        a[mi] = *(const short8*)&As[row * 64 + ((kk * 32 + lh * 8) ^ ((row & 7) * 8))];
      }
      #pragma unroll
      for (int ni = 0; ni < NI; ++ni) {
        int row = wc * (BN / 2) + ni * 16 + l16;
        b[ni] = *(const short8*)&Bs[row * 64 + ((kk * 32 + lh * 8) ^ ((row & 7) * 8))];
      }
      #pragma unroll
      for (int mi = 0; mi < MI; ++mi)
        #pragma unroll
        for (int ni = 0; ni < NI; ++ni)
          acc[mi][ni] = __builtin_amdgcn_mfma_f32_16x16x32_bf16(a[mi], b[ni], acc[mi][ni], 0, 0, 0);
    }
    __syncthreads();
  }
  #pragma unroll
  for (int mi = 0; mi < MI; ++mi)
    #pragma unroll
    for (int ni = 0; ni < NI; ++ni)
      #pragma unroll
      for (int r = 0; r < 4; ++r) {
        size_t row = tm * BM + wr * (BM / 2) + mi * 16 + lh * 4 + r;
        size_t col = tn * BN + wc * (BN / 2) + ni * 16 + l16;
        store_out(&C[row * N + col], acc[mi][ni][r]);
      }
}

// ---------- fused flash attention v10 ----------
// 1024 blocks (XCD-swizzled: 2 heads/XCD) x 256 thr = 4 waves (2 batches x 2 q-groups).
// K: LDS double-buffer (32 KB) via global_load_lds. V: direct global->reg (L2-hit,
// k_tv permutation). bias/mask: registers, 2 steps ahead. Per-step vmem issue order
// [stage K(kt+1) x4][V(kt) x8][bias/mask(kt+2) x5] makes every wait counted:
// PV waits vmcnt(5), bottom waits vmcnt(13), bias consume pre-drained. 3 blocks/CU.
__global__ __launch_bounds__(256, 3) void k_attn(
    const u16* __restrict__ Qp,      // [4096][1024], pre-scaled by 1/8
    const u16* __restrict__ KVp,     // [4096][2048] (cols 0..1023 = K heads)
    const u16* __restrict__ Vt,      // [2048][2048] permuted (see k_tv)
    const float* __restrict__ bias,  // [16][2048][2048]
    const unsigned* __restrict__ mbits, // [2][2048][64]
    u16* __restrict__ Ob)            // [4096][1024]
{
  __shared__ u16 Ks[2 * 2 * 64 * 64];  // [buf][batch][k-row][cb]  32 KB, 16B-XOR
  const int tid = threadIdx.x;         // 0..255
  const int lane = tid & 63;
  const int w = tid >> 6;              // 0..3
  const int bw = w >> 1;               // batch
  const int qg = w & 1;                // q-group (16 rows)
  const int bid = blockIdx.x;          // 0..1023
  const int sid = (bid & 7) * 128 + (bid >> 3);   // XCD-bijective (1024%8==0)
  const int h  = sid >> 6;
  const int qt = sid & 63;
  const int l16 = lane & 15, lh = lane >> 4;
  const int q = qt * 32 + qg * 16 + l16;          // this lane's q row

  // K staging: 4 x 16B chunks/thread/buffer (1024 chunks = 2 batches x 64 rows x 8 cb)
  // flat = i*256+tid: seg=flat>>9 (batch), sub=flat&511, row=sub>>3, cb=sub&7
  // LDS (u16 idx): buf*8192 + seg*4096 + sub*8   (linear dest, pre-swizzled source)

  // V fragment base (R7-proven): row = bw*1024 + h*64 + di*16 + l16, col = kt*64+lh*16+kk*8
  const u16* vfp = Vt + ((size_t)(bw * 1024 + h * 64 + l16)) * 2048 + lh * 16;

  short8 qf[2];
  {
    size_t row = (size_t)bw * 2048 + q;
    qf[0] = *(const short8*)&Qp[row * 1024 + h * 64 + lh * 8];
    qf[1] = *(const short8*)&Qp[row * 1024 + h * 64 + 32 + lh * 8];
  }

  const float* bsrc = bias + ((size_t)h * 2048 + q) * 2048 + lh * 4;
  const u64*   msrc = (const u64*)(mbits + ((size_t)bw * 2048 + q) * 64);

  f32x4 oacc[4] = {};
  f32x4 lpv = {};
  f32x4 biasA[4], biasB[4];
  u64 mwA, mwB;

#define KSTAGE(BUF, KT) do {                                                            \
    _Pragma("unroll")                                                                   \
    for (int i_ = 0; i_ < 4; ++i_) {                                                    \
      const int flat_ = i_ * 256 + tid;                                                 \
      const int seg_ = flat_ >> 9, sub_ = flat_ & 511;                                  \
      const int row_ = sub_ >> 3, cb_ = sub_ & 7;                                       \
      GLOAD16(KVp + ((size_t)(seg_ * 2048 + (KT) * 64 + row_)) * 2048 + h * 64          \
                  + ((cb_ ^ (row_ & 7)) * 8),                                           \
              &Ks[(BUF) * 8192 + seg_ * 4096 + sub_ * 8]);                              \
    }                                                                                   \
  } while (0)

  // ---- prologue: stage kt=0 -> buf0; bias/mask kt=0 -> A, kt=1 -> B ----
  KSTAGE(0, 0);
  #pragma unroll
  for (int ni = 0; ni < 4; ++ni) {
    biasA[ni] = *(const f32x4*)(bsrc + ni * 16);
    biasB[ni] = *(const f32x4*)(bsrc + 64 + ni * 16);
  }
  mwA = msrc[0];
  mwB = msrc[1];
  asm volatile("s_waitcnt vmcnt(0)" ::: "memory");
  __builtin_amdgcn_s_barrier();

  // ASTEP: consume bias set (loaded 2 steps ago, already drained), reload it with kt+2.
#define ASTEP(KT, CUR, BC, MC) do {                                                    \
    const int ktp1_ = ((KT) + 1 < 32) ? (KT) + 1 : 31;                                 \
    const int ktp2_ = ((KT) + 2 < 32) ? (KT) + 2 : 31;                                 \
    KSTAGE((CUR) ^ 1, ktp1_);                                                          \
    short8 vf_[8];                                                                     \
    _Pragma("unroll")                                                                  \
    for (int di = 0; di < 4; ++di)                                                     \
      _Pragma("unroll")                                                                \
      for (int kk = 0; kk < 2; ++kk)                                                   \
        vf_[di * 2 + kk] = *(const short8*)(vfp + (size_t)di * 16 * 2048               \
                                            + (size_t)(KT) * 64 + kk * 8);             \
    f32x4 s_[4];                                                                       \
    s_[0] = BC[0]; s_[1] = BC[1]; s_[2] = BC[2]; s_[3] = BC[3];                        \
    const unsigned tlo_ = (unsigned)(MC) >> (lh * 4);                                  \
    const unsigned thi_ = (unsigned)((MC) >> 32) >> (lh * 4);                          \
    BC[0] = *(const f32x4*)(bsrc + (size_t)ktp2_ * 64 +  0);                           \
    BC[1] = *(const f32x4*)(bsrc + (size_t)ktp2_ * 64 + 16);                           \
    BC[2] = *(const f32x4*)(bsrc + (size_t)ktp2_ * 64 + 32);                           \
    BC[3] = *(const f32x4*)(bsrc + (size_t)ktp2_ * 64 + 48);                           \
    MC = msrc[ktp2_];                                                                  \
    __builtin_amdgcn_sched_barrier(0);                                                 \
    const int kb_ = (CUR) * 8192 + bw * 4096;                                          \
    __builtin_amdgcn_s_setprio(1);                                                     \
    _Pragma("unroll")                                                                  \
    for (int kk = 0; kk < 2; ++kk) {                                                   \
      short8 kf_[4];                                                                   \
      _Pragma("unroll")                                                                \
      for (int ni = 0; ni < 4; ++ni) {                                                 \
        const int row_ = ni * 16 + l16;                                                \
        kf_[ni] = *(const short8*)&Ks[kb_ + row_ * 64 + ((kk * 32 + lh * 8) ^ ((row_ & 7) * 8))]; \
      }                                                                                \
      _Pragma("unroll")                                                                \
      for (int ni = 0; ni < 4; ++ni)                                                   \
        s_[ni] = __builtin_amdgcn_mfma_f32_16x16x32_bf16(kf_[ni], qf[kk], s_[ni], 0, 0, 0); \
    }                                                                                  \
    __builtin_amdgcn_s_setprio(0);                                                     \
    union pfu_ { u32 wd[4]; short8 v; };                                               \
    union pfu_ pf_[2];                                                                 \
    _Pragma("unroll")                                                                  \
    for (int ni = 0; ni < 4; ++ni) {                                                   \
      const unsigned tw_ = (ni < 2) ? tlo_ : thi_;                                     \
      _Pragma("unroll")                                                                \
      for (int r = 0; r < 4; ++r) {                                                    \
        const unsigned bit_ = (tw_ >> ((ni & 1) * 16 + r)) & 1u;                       \
        s_[ni][r] = bit_ ? __expf(s_[ni][r]) : 0.f;                                    \
      }                                                                                \
      lpv += s_[ni];                                                                   \
      asm("v_cvt_pk_bf16_f32 %0, %1, %2" : "=v"(pf_[ni >> 1].wd[2 * (ni & 1)])     : "v"(s_[ni][0]), "v"(s_[ni][1])); \
      asm("v_cvt_pk_bf16_f32 %0, %1, %2" : "=v"(pf_[ni >> 1].wd[2 * (ni & 1) + 1]) : "v"(s_[ni][2]), "v"(s_[ni][3])); \
    }                                                                                  \
    __builtin_amdgcn_s_setprio(1);                                                     \
    _Pragma("unroll")                                                                  \
    for (int kk = 0; kk < 2; ++kk)                                                     \
      _Pragma("unroll")                                                                \
      for (int di = 0; di < 4; ++di)                                                   \
        oacc[di] = __builtin_amdgcn_mfma_f32_16x16x32_bf16(vf_[di * 2 + kk], pf_[kk].v, oacc[di], 0, 0, 0); \
    __builtin_amdgcn_s_setprio(0);                                                     \
    asm volatile("s_waitcnt lgkmcnt(0)" ::: "memory");                                 \
    asm volatile("s_waitcnt vmcnt(13)" ::: "memory");                                  \
    __builtin_amdgcn_s_barrier();                                                      \
  } while (0)

  for (int kt2 = 0; kt2 < 32; kt2 += 2) {
    ASTEP(kt2,     0, biasA, mwA);
    ASTEP(kt2 + 1, 1, biasB, mwB);
  }
#undef ASTEP
#undef KSTAGE

  // ---- epilogue: reduce row-sum across lh groups, divide, pack, store ----
  float lpart = lpv[0] + lpv[1] + lpv[2] + lpv[3];
  lpart += __shfl_xor(lpart, 16);
  lpart += __shfl_xor(lpart, 32);
  float inv = 1.0f / lpart;
  size_t orow = (size_t)bw * 2048 + q;
  #pragma unroll
  for (int di = 0; di < 4; ++di)
    #pragma unroll
    for (int rp = 0; rp < 2; ++rp) {
      float v0 = oacc[di][2 * rp] * inv;
      float v1 = oacc[di][2 * rp + 1] * inv;
      u32 pk;
      asm("v_cvt_pk_bf16_f32 %0, %1, %2" : "=v"(pk) : "v"(v0), "v"(v1));
      *(u32*)&Ob[orow * 1024 + h * 64 + di * 16 + lh * 4 + rp * 2] = pk;
    }
}

extern "C" void kernel_launch(void* const* d_in, const int* in_sizes, int n_in,
                              void* d_out, int out_size, void* d_ws, size_t ws_size,
                              hipStream_t stream) {
  const float* query     = (const float*)d_in[0];
  const float* key_value = (const float*)d_in[1];
  const int*   mask      = (const int*)d_in[2];
  const float* bias      = (const float*)d_in[3];
  const float* Wq        = (const float*)d_in[4];
  const float* Wkv       = (const float*)d_in[5];
  const float* Wo        = (const float*)d_in[6];
  float* out = (float*)d_out;

  char* ws = (char*)d_ws;
  u16* qb   = (u16*)(ws);                    // 8 MiB  bf16 query
  u16* kvb  = (u16*)(ws + 8388608);          // 8 MiB  bf16 key_value
  u16* WqT  = (u16*)(ws + 16777216);         // 2 MiB  Wq^T * 0.125
  u16* WkvT = (u16*)(ws + 18874368);         // 4 MiB  Wkv^T
  u16* WoT  = (u16*)(ws + 23068672);         // 2 MiB  Wo^T
  u16* Qp   = (u16*)(ws + 25165824);         // 8 MiB  projected q
  u16* KVp  = (u16*)(ws + 33554432);         // 16 MiB projected kv
  u16* Vt   = (u16*)(ws + 50331648);         // 8 MiB  V transposed+permuted
  u16* Ob   = (u16*)(ws + 58720256);         // 8 MiB  attention out
  unsigned* mb = (unsigned*)(ws + 67108864); // 1 MiB  packed mask

  dim3 tb(32, 8);
  k_cvt<<<4096, 256, 0, stream>>>(query, qb, 1048576);
  k_cvt<<<4096, 256, 0, stream>>>(key_value, kvb, 1048576);
  k_tcvt<<<dim3(32, 32), tb, 0, stream>>>(Wq,  WqT,  1024, 1024, 0.125f);
  k_tcvt<<<dim3(64, 32), tb, 0, stream>>>(Wkv, WkvT, 1024, 2048, 1.0f);
  k_tcvt<<<dim3(32, 32), tb, 0, stream>>>(Wo,  WoT,  1024, 1024, 1.0f);
  k_pm<<<1024, 256, 0, stream>>>(mask, mb, 262144);
  k_gemm<64, 128, u16><<<dim3(64, 8),  256, 0, stream>>>(qb,  WqT,  Qp,  4096, 1024, 1024);
  k_gemm<64, 128, u16><<<dim3(64, 16), 256, 0, stream>>>(kvb, WkvT, KVp, 4096, 2048, 1024);
  k_tv<<<dim3(64, 32, 2), tb, 0, stream>>>(KVp, Vt);
  k_attn<<<1024, 256, 0, stream>>>(Qp, KVp, Vt, bias, mb, Ob);
  k_gemm<64, 128, float><<<dim3(64, 8), 256, 0, stream>>>(Ob, WoT, out, 4096, 1024, 1024);
}